// Round 11
// baseline (368.715 us; speedup 1.0000x reference)
//
#include <hip/hip_runtime.h>
#include <cstdint>
#include <cstddef>

// ---------------- problem constants ----------------
#define NN 50000
#define EE 1600000
#define IN_DIM 256
#define HC 128      // HEADS*C
#define CD 32       // C
#define BN_RS 0.9999950000374997f  // 1/sqrt(1+1e-5)

#define CAP1 128
#define CAP2 128
#define NBKT 196        // ceil(NN/256) buckets of 256 dst nodes
#define S1_B 782        // (EE+2047)/2048
#define HIST_B 160
#define G1_B 782        // gemm1 blocks (4 waves x 16 rows)
#define PADW 136        // LDS h1 row stride (ushorts): 272B, 16B-aligned, 2-way banks

typedef __attribute__((ext_vector_type(8))) short short8;   // 8 bf16 (bit pattern)
typedef __attribute__((ext_vector_type(4))) float f32x4;

// ---------------- small helpers ----------------
__device__ __forceinline__ float lrelu(float a) { return a > 0.f ? a : 0.2f * a; }
__device__ __forceinline__ float elu(float a) { return a > 0.f ? a : (__expf(a) - 1.f); }

__device__ __forceinline__ unsigned short f2bf(float f) {
    unsigned int u = __float_as_uint(f);
    unsigned int r = (u + 0x7FFFu + ((u >> 16) & 1u)) >> 16;
    return (unsigned short)r;
}
__device__ __forceinline__ float bf2f(unsigned short b) {
    return __uint_as_float(((unsigned int)b) << 16);
}
__device__ __forceinline__ float2 bf2f2(unsigned int p) {
    float2 r;
    r.x = __uint_as_float(p << 16);
    r.y = __uint_as_float(p & 0xFFFF0000u);
    return r;
}
__device__ __forceinline__ void unpack_edge(unsigned long long p, int& s, float& eav) {
    s = (int)(unsigned int)(p & 0xFFFFFFFFull);
    eav = __uint_as_float((unsigned int)(p >> 32));
}

// 256-thread exclusive scan (ONE internal barrier; all 256 must call)
__device__ __forceinline__ int block_excl_scan_256(int v, int tid, int* wsum) {
    int lane = tid & 63, wv = tid >> 6;
    int x = v;
    #pragma unroll
    for (int off = 1; off < 64; off <<= 1) {
        int y = __shfl_up(x, off);
        if (lane >= off) x += y;
    }
    if (lane == 63) wsum[wv] = x;
    __syncthreads();
    int wpre = 0;
    #pragma unroll
    for (int w = 0; w < 4; w++)
        if (w < wv) wpre += wsum[w];
    return wpre + x - v;
}

// ---------------- K0: W1/W2 frag prepack + attn consts + zero-init ----------------
__global__ __launch_bounds__(256) void k0_prep(const float* __restrict__ W1,
                                               const float* __restrict__ W2,
                                               const float* __restrict__ We1,
                                               const float* __restrict__ ae1,
                                               const float* __restrict__ We2,
                                               const float* __restrict__ ae2,
                                               unsigned short* __restrict__ W1hi,
                                               unsigned short* __restrict__ W1lo,
                                               unsigned short* __restrict__ W2hi,
                                               unsigned short* __restrict__ W2lo,
                                               float* __restrict__ consts,
                                               int* __restrict__ bucketHist) {
    int blk = blockIdx.x;
    int tid = threadIdx.x;
    if (blk < 16) {
        // W1 [256,128] -> frag order ((nt*8+kt)*64+lane)*8+j, split hi/lo
        int t = blk * 256 + tid;
        int lane = t & 63;
        int kt = (t >> 6) & 7;
        int nt = t >> 9;
        int kbase = kt * 32 + (lane >> 4) * 8;
        int col = nt * 16 + (lane & 15);
        size_t obase = (size_t)t * 8;
        #pragma unroll
        for (int j = 0; j < 8; j++) {
            float w = W1[(size_t)(kbase + j) * HC + col];
            unsigned short h = f2bf(w);
            W1hi[obase + j] = h;
            W1lo[obase + j] = f2bf(w - bf2f(h));
        }
    } else if (blk < 18) {
        // W2 [128,32] -> frag order ((nt*4+kt)*64+lane)*8+j, split hi/lo
        int t = (blk - 16) * 256 + tid;  // 0..511
        int lane = t & 63;
        int kt = (t >> 6) & 3;
        int nt = t >> 8;
        int kbase = kt * 32 + (lane >> 4) * 8;
        int col = nt * 16 + (lane & 15);
        size_t obase = (size_t)t * 8;
        #pragma unroll
        for (int j = 0; j < 8; j++) {
            float w = W2[(size_t)(kbase + j) * CD + col];
            unsigned short h = f2bf(w);
            W2hi[obase + j] = h;
            W2lo[obase + j] = f2bf(w - bf2f(h));
        }
    } else {
        if (tid < NBKT) bucketHist[tid] = 0;
        if (tid == 200) consts[0] = 0.f;     // easum accumulator
        if (tid < 4) {
            float s = 0.f;
            for (int c = 0; c < 32; c++) s += We1[tid * 32 + c] * ae1[tid * 32 + c];
            consts[2 + tid] = s;
        } else if (tid == 4) {
            float s = 0.f;
            for (int c = 0; c < 32; c++) s += We2[c] * ae2[c];
            consts[6] = s;
        }
    }
}

// ---------------- K_A: hist (LDS) + gemm1 (MFMA split-bf16), fused ----------------
__global__ __launch_bounds__(256) void kA_hist_gemm1(const int* __restrict__ ei,
                                                     const float* __restrict__ ea,
                                                     const float* __restrict__ x,
                                                     const unsigned short* __restrict__ Whi,
                                                     const unsigned short* __restrict__ Wlo,
                                                     int* __restrict__ bucketHist,
                                                     float* __restrict__ easum,
                                                     unsigned short* __restrict__ xs1b) {
    __shared__ int h[256];
    int tid = threadIdx.x;
    if (blockIdx.x < HIST_B) {
        h[tid] = 0;
        __syncthreads();
        float s = 0.f;
        for (int i = blockIdx.x * 256 + tid; i < EE; i += HIST_B * 256) {
            atomicAdd(&h[ei[EE + i] >> 8], 1);
            s += ea[i];
        }
        __syncthreads();
        if (tid < NBKT && h[tid] > 0) atomicAdd(&bucketHist[tid], h[tid]);
        #pragma unroll
        for (int off = 32; off > 0; off >>= 1) s += __shfl_xor(s, off);
        if ((tid & 63) == 0) atomicAdd(easum, s);
    } else {
        int lane = tid & 63, wv = tid >> 6;
        int row0 = (blockIdx.x - HIST_B) * 64 + wv * 16;
        if (row0 >= NN) return;
        int m = lane & 15;
        int q = lane >> 4;
        f32x4 acc[8];
        #pragma unroll
        for (int nt = 0; nt < 8; nt++) acc[nt] = {0.f, 0.f, 0.f, 0.f};
        const float* xrow = x + (size_t)(row0 + m) * IN_DIM + q * 8;
        #pragma unroll
        for (int kt = 0; kt < 8; kt++) {
            float4 v0 = *(const float4*)(xrow + kt * 32);
            float4 v1 = *(const float4*)(xrow + kt * 32 + 4);
            float vv[8] = {v0.x, v0.y, v0.z, v0.w, v1.x, v1.y, v1.z, v1.w};
            short8 ahi, alo;
            #pragma unroll
            for (int j = 0; j < 8; j++) {
                unsigned short hh = f2bf(vv[j]);
                ahi[j] = (short)hh;
                alo[j] = (short)f2bf(vv[j] - bf2f(hh));
            }
            #pragma unroll
            for (int nt = 0; nt < 8; nt++) {
                size_t fb = ((size_t)(nt * 8 + kt) * 64 + lane) * 8;
                short8 bhi = *(const short8*)(Whi + fb);
                short8 blo = *(const short8*)(Wlo + fb);
                acc[nt] = __builtin_amdgcn_mfma_f32_16x16x32_bf16(ahi, bhi, acc[nt], 0, 0, 0);
                acc[nt] = __builtin_amdgcn_mfma_f32_16x16x32_bf16(ahi, blo, acc[nt], 0, 0, 0);
                acc[nt] = __builtin_amdgcn_mfma_f32_16x16x32_bf16(alo, bhi, acc[nt], 0, 0, 0);
            }
        }
        #pragma unroll
        for (int nt = 0; nt < 8; nt++) {
            #pragma unroll
            for (int reg = 0; reg < 4; reg++) {
                int row = row0 + q * 4 + reg;
                xs1b[(size_t)row * HC + nt * 16 + m] = f2bf(acc[nt][reg]);
            }
        }
    }
}

// ---------------- bucket scan: bases + cursors + sentinels + ea_mean ----------------
__global__ void bucket_scan(const int* __restrict__ bucketHist,
                            int* __restrict__ bucketBase,
                            int* __restrict__ bucketCursor,
                            int* __restrict__ indptr,
                            float* __restrict__ consts) {
    __shared__ int wsum[4];
    int tid = threadIdx.x;  // 256
    int v = (tid < NBKT) ? bucketHist[tid] : 0;
    int excl = block_excl_scan_256(v, tid, wsum);
    if (tid <= NBKT) bucketBase[tid] = (tid == NBKT) ? EE : excl;
    if (tid < NBKT) bucketCursor[tid] = excl;
    if (tid == 0) { indptr[NN] = EE; consts[1] = consts[0] / (float)EE; }
}

// ---------------- K_B: stage1 (bucket bin) + al1, fused ----------------
__global__ __launch_bounds__(256) void kB_stage1_al1(const int* __restrict__ ei,
                                                     const float* __restrict__ ea,
                                                     int* __restrict__ bucketCursor,
                                                     int* __restrict__ Adst,
                                                     int* __restrict__ Asrc,
                                                     float* __restrict__ Aea,
                                                     const unsigned short* __restrict__ xs1b,
                                                     const float* __restrict__ as1,
                                                     const float* __restrict__ ad1,
                                                     float* __restrict__ als,
                                                     float* __restrict__ ald) {
    __shared__ int cnt[256];
    __shared__ int basel[256];
    __shared__ int gbase[256];
    __shared__ int wsum[4];
    __shared__ int sdst[2048];
    __shared__ int ssrc[2048];
    __shared__ float sea[2048];
    int tid = threadIdx.x;
    if (blockIdx.x < S1_B) {
        int base = blockIdx.x * 2048;
        cnt[tid] = 0;
        __syncthreads();
        int d[8], s[8], r[8], bk[8];
        float e[8];
        #pragma unroll
        for (int k = 0; k < 8; k++) {
            int i = base + k * 256 + tid;
            if (i < EE) {
                d[k] = ei[EE + i];
                s[k] = ei[i];
                e[k] = ea[i];
                bk[k] = d[k] >> 8;
                r[k] = atomicAdd(&cnt[bk[k]], 1);   // LDS returning atomic: cheap
            } else d[k] = -1;
        }
        __syncthreads();
        int v = cnt[tid];
        int excl = block_excl_scan_256(v, tid, wsum);
        basel[tid] = excl;
        if (tid < NBKT) gbase[tid] = atomicAdd(&bucketCursor[tid], v);
        __syncthreads();
        #pragma unroll
        for (int k = 0; k < 8; k++) {
            if (d[k] >= 0) {
                int slot = basel[bk[k]] + r[k];
                sdst[slot] = d[k];
                ssrc[slot] = s[k];
                sea[slot] = e[k];
            }
        }
        __syncthreads();
        int total = basel[255] + cnt[255];
        for (int slot = tid; slot < total; slot += 256) {
            int dd = sdst[slot];
            int b = dd >> 8;
            int pos = gbase[b] + (slot - basel[b]);
            Adst[pos] = dd;
            Asrc[pos] = ssrc[slot];
            Aea[pos] = sea[slot];
        }
    } else {
        // ---- al1 path: one thread per (node,head) ----
        int t = (blockIdx.x - S1_B) * 256 + tid;
        if (t < NN * 4) {
            int hh = t & 3;
            const unsigned int* xp = (const unsigned int*)(xs1b + (size_t)t * 32);
            const float* ap = as1 + hh * 32;
            const float* dp = ad1 + hh * 32;
            float s = 0.f, d = 0.f;
            #pragma unroll
            for (int q = 0; q < 16; q++) {
                float2 v = bf2f2(xp[q]);
                s += v.x * ap[q * 2] + v.y * ap[q * 2 + 1];
                d += v.x * dp[q * 2] + v.y * dp[q * 2 + 1];
            }
            als[t] = s;
            ald[t] = d;
        }
    }
}

// ---------------- stage2: per-bucket counting sort -> indptr + edgedat ----------------
__global__ __launch_bounds__(256) void stage2_kernel(const int* __restrict__ bucketBase,
                                                     const int* __restrict__ Adst,
                                                     const int* __restrict__ Asrc,
                                                     const float* __restrict__ Aea,
                                                     int* __restrict__ indptr,
                                                     unsigned long long* __restrict__ edgedat) {
    __shared__ int cnt[256];
    __shared__ int dbase[256];
    __shared__ int wsum[4];
    int tid = threadIdx.x;
    int b = blockIdx.x;
    int start = bucketBase[b], end = bucketBase[b + 1];
    cnt[tid] = 0;
    __syncthreads();
    for (int i = start + tid; i < end; i += 256) atomicAdd(&cnt[Adst[i] & 255], 1);
    __syncthreads();
    int v = cnt[tid];
    int excl = block_excl_scan_256(v, tid, wsum);
    dbase[tid] = excl;
    __syncthreads();
    int n = b * 256 + tid;
    if (n < NN) indptr[n] = start + excl;
    cnt[tid] = 0;          // reuse as per-dst cursor
    __syncthreads();
    for (int i = start + tid; i < end; i += 256) {
        int dl = Adst[i] & 255;
        int r = atomicAdd(&cnt[dl], 1);
        int pos = start + dbase[dl] + r;
        edgedat[pos] = (unsigned long long)(unsigned int)Asrc[i] |
                       ((unsigned long long)__float_as_uint(Aea[i]) << 32);
    }
}

// ---------------- gat1 fused: conv1 agg (16 nodes/block) + in-LDS gemm2 + al2 ----------------
__global__ __launch_bounds__(256) void gat1_fused(
    const unsigned short* __restrict__ xs1b, const float* __restrict__ als,
    const float* __restrict__ ald, const unsigned long long* __restrict__ edgedat,
    const int* __restrict__ indptr, const float* __restrict__ consts,
    const float* __restrict__ b1, const float* __restrict__ g1,
    const float* __restrict__ be1,
    const unsigned short* __restrict__ W2hi, const unsigned short* __restrict__ W2lo,
    const float* __restrict__ as2, const float* __restrict__ ad2,
    unsigned short* __restrict__ xs2b, float* __restrict__ als2, float* __restrict__ ald2) {
    __shared__ float exbuf[4][CAP1 * 4];
    __shared__ int srcbuf[4][CAP1];
    __shared__ unsigned short h1hiL[16][PADW];
    __shared__ unsigned short h1loL[16][PADW];
    __shared__ float sred[4][16];
    int wv = threadIdx.x >> 6;
    int lane = threadIdx.x & 63;
    int c = lane * 2;
    int h = lane >> 4;
    float ea_mean = consts[1];
    float ce[4] = {consts[2], consts[3], consts[4], consts[5]};
    // ---- phase A: GAT1 aggregation for 4 nodes per wave (serial) ----
    for (int t = 0; t < 4; t++) {
        int n = blockIdx.x * 16 + wv * 4 + t;   // 3125*16 = 50000 exact
        int start = indptr[n];
        int deg = indptr[n + 1] - start;
        float4 a4d = *(const float4*)(ald + (size_t)n * 4);
        float aldh[4] = {a4d.x, a4d.y, a4d.z, a4d.w};
        float4 a4s = *(const float4*)(als + (size_t)n * 4);
        float alsn[4] = {a4s.x, a4s.y, a4s.z, a4s.w};
        float ex0[4], sm[4];
        #pragma unroll
        for (int hh = 0; hh < 4; hh++) {
            ex0[hh] = __expf(lrelu(alsn[hh] + aldh[hh] + ea_mean * ce[hh]));
            sm[hh] = 0.f;
        }
        const unsigned long long* edp = edgedat + start;
        for (int i = lane; i < deg; i += 64) {
            int s; float eav;
            unpack_edge(edp[i], s, eav);
            float4 v4 = *(const float4*)(als + (size_t)s * 4);
            float alv[4] = {v4.x, v4.y, v4.z, v4.w};
            bool st = (i < CAP1);
            if (st) srcbuf[wv][i] = s * HC;
            #pragma unroll
            for (int hh = 0; hh < 4; hh++) {
                float exv = __expf(lrelu(alv[hh] + aldh[hh] + eav * ce[hh]));
                if (st) exbuf[wv][i * 4 + hh] = exv;
                sm[hh] += exv;
            }
        }
        #pragma unroll
        for (int hh = 0; hh < 4; hh++)
            for (int off = 32; off > 0; off >>= 1) sm[hh] += __shfl_xor(sm[hh], off);
        float inv[4];
        #pragma unroll
        for (int hh = 0; hh < 4; hh++) inv[hh] = 1.0f / (sm[hh] + ex0[hh] + 1e-16f);
        int mcap = deg < CAP1 ? deg : CAP1;
        for (int i = lane; i < mcap; i += 64) {
            #pragma unroll
            for (int hh = 0; hh < 4; hh++) exbuf[wv][i * 4 + hh] *= inv[hh];
        }
        float wsl = ex0[h] * inv[h];
        float2 vself = bf2f2(*(const unsigned int*)(xs1b + (size_t)n * HC + c));
        float accx = vself.x * wsl, accy = vself.y * wsl;
        int i = 0;
        for (; i + 4 <= mcap; i += 4) {
            float w0 = exbuf[wv][(i + 0) * 4 + h];
            float w1 = exbuf[wv][(i + 1) * 4 + h];
            float w2 = exbuf[wv][(i + 2) * 4 + h];
            float w3 = exbuf[wv][(i + 3) * 4 + h];
            int o0 = srcbuf[wv][i + 0], o1 = srcbuf[wv][i + 1];
            int o2 = srcbuf[wv][i + 2], o3 = srcbuf[wv][i + 3];
            float2 v0 = bf2f2(*(const unsigned int*)(xs1b + o0 + c));
            float2 v1 = bf2f2(*(const unsigned int*)(xs1b + o1 + c));
            float2 v2 = bf2f2(*(const unsigned int*)(xs1b + o2 + c));
            float2 v3 = bf2f2(*(const unsigned int*)(xs1b + o3 + c));
            accx += v0.x * w0; accy += v0.y * w0;
            accx += v1.x * w1; accy += v1.y * w1;
            accx += v2.x * w2; accy += v2.y * w2;
            accx += v3.x * w3; accy += v3.y * w3;
        }
        for (; i < mcap; i++) {
            float w0 = exbuf[wv][i * 4 + h];
            int o0 = srcbuf[wv][i];
            float2 v0 = bf2f2(*(const unsigned int*)(xs1b + o0 + c));
            accx += v0.x * w0; accy += v0.y * w0;
        }
        for (; i < deg; i++) {  // spill fallback (deg > CAP1): recompute
            int s; float eav;
            unpack_edge(edp[i], s, eav);
            float a = lrelu(als[(size_t)s * 4 + h] + aldh[h] + eav * ce[h]);
            float w0 = __expf(a) * inv[h];
            float2 v0 = bf2f2(*(const unsigned int*)(xs1b + (size_t)s * HC + c));
            accx += v0.x * w0; accy += v0.y * w0;
        }
        float o0 = accx + b1[c];
        float o1 = accy + b1[c + 1];
        o0 = o0 * (g1[c] * BN_RS) + be1[c];
        o1 = o1 * (g1[c + 1] * BN_RS) + be1[c + 1];
        o0 = elu(o0);
        o1 = elu(o1);
        // write h1 hi/lo into the block's LDS tile (row = wv*4+t)
        int lrow = wv * 4 + t;
        unsigned short h0 = f2bf(o0), h1v = f2bf(o1);
        unsigned short l0 = f2bf(o0 - bf2f(h0)), l1 = f2bf(o1 - bf2f(h1v));
        *(unsigned int*)&h1hiL[lrow][c] = (unsigned int)h0 | ((unsigned int)h1v << 16);
        *(unsigned int*)&h1loL[lrow][c] = (unsigned int)l0 | ((unsigned int)l1 << 16);
    }
    __syncthreads();
    // ---- phase B: gemm2 (16x32, K=128) from LDS + fused al2 ----
    if (wv < 2) {
        int m = lane & 15, q = lane >> 4;
        f32x4 acc = {0.f, 0.f, 0.f, 0.f};
        #pragma unroll
        for (int kt = 0; kt < 4; kt++) {
            short8 ahi = *(const short8*)&h1hiL[m][kt * 32 + q * 8];
            short8 alo = *(const short8*)&h1loL[m][kt * 32 + q * 8];
            size_t fb = ((size_t)(wv * 4 + kt) * 64 + lane) * 8;
            short8 bhi = *(const short8*)(W2hi + fb);
            short8 blo = *(const short8*)(W2lo + fb);
            acc = __builtin_amdgcn_mfma_f32_16x16x32_bf16(ahi, bhi, acc, 0, 0, 0);
            acc = __builtin_amdgcn_mfma_f32_16x16x32_bf16(ahi, blo, acc, 0, 0, 0);
            acc = __builtin_amdgcn_mfma_f32_16x16x32_bf16(alo, bhi, acc, 0, 0, 0);
        }
        float a0 = as2[wv * 16 + m];
        float d0 = ad2[wv * 16 + m];
        #pragma unroll
        for (int reg = 0; reg < 4; reg++) {
            int lrow = q * 4 + reg;
            int row = blockIdx.x * 16 + lrow;
            xs2b[(size_t)row * CD + wv * 16 + m] = f2bf(acc[reg]);
            float s = acc[reg] * a0;
            float d = acc[reg] * d0;
            #pragma unroll
            for (int off = 1; off < 16; off <<= 1) {
                s += __shfl_xor(s, off);
                d += __shfl_xor(d, off);
            }
            if (m == 0) { sred[wv * 2 + 0][lrow] = s; sred[wv * 2 + 1][lrow] = d; }
        }
    }
    __syncthreads();
    if (threadIdx.x < 16) {
        int row = blockIdx.x * 16 + threadIdx.x;
        als2[row] = sred[0][threadIdx.x] + sred[2][threadIdx.x];
        ald2[row] = sred[1][threadIdx.x] + sred[3][threadIdx.x];
    }
}

// ---------------- conv2 aggregation + fused MLP heads (no-max softmax) ----------------
__global__ __launch_bounds__(256) void gat2_agg(
    const unsigned short* __restrict__ xs2b, const float* __restrict__ als,
    const float* __restrict__ ald, const unsigned long long* __restrict__ edgedat,
    const int* __restrict__ indptr, const float* __restrict__ consts,
    const float* __restrict__ b2, const float* __restrict__ g2, const float* __restrict__ be2,
    const float* __restrict__ Wc1, const float* __restrict__ bc1,
    const float* __restrict__ Wc2, const float* __restrict__ bc2,
    const float* __restrict__ Wr1, const float* __restrict__ br1,
    const float* __restrict__ Wr2, const float* __restrict__ br2,
    float* __restrict__ hout, float* __restrict__ cls, float* __restrict__ reg) {
    __shared__ float exbuf[4][CAP2];
    __shared__ int srcbuf[4][CAP2];
    __shared__ float hbuf[4][32];
    int wv = threadIdx.x >> 6;
    int lane = threadIdx.x & 63;
    int n = blockIdx.x * 4 + wv;
    int start = indptr[n];
    int deg = indptr[n + 1] - start;
    float ea_mean = consts[1];
    float ce = consts[6];
    float aldn = ald[n];
    float ex0 = __expf(lrelu(als[n] + aldn + ea_mean * ce));
    float sm = 0.f;
    const unsigned long long* edp = edgedat + start;
    for (int i = lane; i < deg; i += 64) {
        int s; float eav;
        unpack_edge(edp[i], s, eav);
        float exv = __expf(lrelu(als[s] + aldn + eav * ce));
        if (i < CAP2) { srcbuf[wv][i] = s * CD; exbuf[wv][i] = exv; }
        sm += exv;
    }
    for (int off = 32; off > 0; off >>= 1) sm += __shfl_xor(sm, off);
    float invd = 1.0f / (sm + ex0 + 1e-16f);
    int mcap = deg < CAP2 ? deg : CAP2;
    for (int i = lane; i < mcap; i += 64) exbuf[wv][i] *= invd;
    int quarter = lane >> 4;
    int cl = lane & 15;
    int c = cl * 2;
    float accx = 0.f, accy = 0.f;
    if (quarter == 0) {
        float2 vs = bf2f2(*(const unsigned int*)(xs2b + (size_t)n * CD + c));
        float wsl = ex0 * invd;
        accx = vs.x * wsl; accy = vs.y * wsl;
    }
    for (int i = quarter; i < mcap; i += 4) {
        float w0 = exbuf[wv][i];
        int o0 = srcbuf[wv][i];
        float2 v0 = bf2f2(*(const unsigned int*)(xs2b + o0 + c));
        accx += v0.x * w0; accy += v0.y * w0;
    }
    for (int i = CAP2 + quarter; i < deg; i += 4) {  // spill fallback
        int s; float eav;
        unpack_edge(edp[i], s, eav);
        float w0 = __expf(lrelu(als[s] + aldn + eav * ce)) * invd;
        float2 v0 = bf2f2(*(const unsigned int*)(xs2b + (size_t)s * CD + c));
        accx += v0.x * w0; accy += v0.y * w0;
    }
    accx += __shfl_xor(accx, 16); accy += __shfl_xor(accy, 16);
    accx += __shfl_xor(accx, 32); accy += __shfl_xor(accy, 32);
    if (lane < 16) {
        float o0 = accx + b2[c];
        float o1 = accy + b2[c + 1];
        o0 = o0 * (g2[c] * BN_RS) + be2[c];
        o1 = o1 * (g2[c + 1] * BN_RS) + be2[c + 1];
        o0 = elu(o0);
        o1 = elu(o1);
        hbuf[wv][c] = o0;
        hbuf[wv][c + 1] = o1;
        *(float2*)(hout + (size_t)n * CD + c) = make_float2(o0, o1);
    }
    __syncthreads();
    float r0 = 0.f, r1 = 0.f;
    if (lane < 32) {
        int j = lane & 15;
        bool iscls = lane < 16;
        float s = iscls ? bc1[j] : br1[j];
        #pragma unroll
        for (int cc = 0; cc < 32; cc++) {
            float w = iscls ? Wc1[cc * 16 + j] : Wr1[cc * 16 + j];
            s += hbuf[wv][cc] * w;
        }
        s = fmaxf(s, 0.f);
        if (iscls) { r0 = s * Wc2[j * 2]; r1 = s * Wc2[j * 2 + 1]; }
        else       { r0 = s * Wr2[j]; }
    }
    #pragma unroll
    for (int off = 1; off < 16; off <<= 1) {
        r0 += __shfl_xor(r0, off);
        r1 += __shfl_xor(r1, off);
    }
    if (lane == 0)  *(float2*)(cls + (size_t)n * 2) = make_float2(r0 + bc2[0], r1 + bc2[1]);
    if (lane == 16) reg[n] = r0 + br2[0];
}

// ---------------- launch ----------------
extern "C" void kernel_launch(void* const* d_in, const int* in_sizes, int n_in,
                              void* d_out, int out_size, void* d_ws, size_t ws_size,
                              hipStream_t stream) {
    const float* x   = (const float*)d_in[0];
    const int*   ei  = (const int*)d_in[1];
    const float* ea  = (const float*)d_in[2];
    const float* W1  = (const float*)d_in[3];
    const float* as1 = (const float*)d_in[4];
    const float* ad1 = (const float*)d_in[5];
    const float* We1 = (const float*)d_in[6];
    const float* ae1 = (const float*)d_in[7];
    const float* b1  = (const float*)d_in[8];
    const float* g1  = (const float*)d_in[9];
    const float* be1 = (const float*)d_in[10];
    const float* W2  = (const float*)d_in[11];
    const float* as2 = (const float*)d_in[12];
    const float* ad2 = (const float*)d_in[13];
    const float* We2 = (const float*)d_in[14];
    const float* ae2 = (const float*)d_in[15];
    const float* b2  = (const float*)d_in[16];
    const float* g2  = (const float*)d_in[17];
    const float* be2 = (const float*)d_in[18];
    const float* Wc1 = (const float*)d_in[19];
    const float* bc1 = (const float*)d_in[20];
    const float* Wc2 = (const float*)d_in[21];
    const float* bc2 = (const float*)d_in[22];
    const float* Wr1 = (const float*)d_in[23];
    const float* br1 = (const float*)d_in[24];
    const float* Wr2 = (const float*)d_in[25];
    const float* br2 = (const float*)d_in[26];

    char* ws = (char*)d_ws;
    unsigned short* xs1b = (unsigned short*)(ws + 0);          // N*128 bf16 = 12.8 MB
    int*   Adst          = (int*)(ws + 12800000);              // E = 6.4 MB
    int*   Asrc          = (int*)(ws + 19200000);              // E = 6.4 MB
    float* Aea           = (float*)(ws + 25600000);            // E = 6.4 MB (ends 32.0 MB)
    unsigned short* xs2b = (unsigned short*)(ws + 38400000);   // N*32 bf16 = 3.2 MB
    float* als1          = (float*)(ws + 41600000);            // N*4
    float* ald1          = (float*)(ws + 42400000);            // N*4
    float* als2          = (float*)(ws + 43200000);            // N
    float* ald2          = (float*)(ws + 43400000);            // N
    float* consts        = (float*)(ws + 43600000);            // 8 floats
    int*   bucketHist    = (int*)(ws + 43600128);              // 196
    int*   bucketBase    = (int*)(ws + 43601024);              // 197
    int*   bucketCursor  = (int*)(ws + 43601920);              // 196
    int*   indptr        = (int*)(ws + 43602816);              // N+1
    unsigned long long* edgedat = (unsigned long long*)(ws + 43802824);  // E*8 -> ends 56602824
    unsigned short* W1hi = (unsigned short*)(ws + 56602832);   // 64 KB
    unsigned short* W1lo = (unsigned short*)(ws + 56668368);   // 64 KB
    unsigned short* W2hi = (unsigned short*)(ws + 56733904);   // 8 KB
    unsigned short* W2lo = (unsigned short*)(ws + 56742096);   // 8 KB (ends ~56.75 MB)

    float* out_cls = (float*)d_out;            // [N,2]
    float* out_reg = out_cls + 2 * NN;         // [N]
    float* out_h   = out_cls + 3 * NN;         // [N,32]

    // K0: weight prepacks + attn consts + zero-init (replaces memsets)
    k0_prep<<<19, 256, 0, stream>>>(W1, W2, We1, ae1, We2, ae2,
                                    W1hi, W1lo, W2hi, W2lo, consts, bucketHist);
    // K_A: hist + gemm1 fused
    kA_hist_gemm1<<<HIST_B + G1_B, 256, 0, stream>>>(ei, ea, x, W1hi, W1lo,
                                                     bucketHist, consts, xs1b);
    bucket_scan<<<1, 256, 0, stream>>>(bucketHist, bucketBase, bucketCursor, indptr, consts);
    // K_B: stage1 + al1 fused
    kB_stage1_al1<<<S1_B + 782, 256, 0, stream>>>(ei, ea, bucketCursor, Adst, Asrc, Aea,
                                                  xs1b, as1, ad1, als1, ald1);
    stage2_kernel<<<NBKT, 256, 0, stream>>>(bucketBase, Adst, Asrc, Aea, indptr, edgedat);

    // gat1 + in-LDS gemm2 + al2 (h1 never touches global memory)
    gat1_fused<<<NN / 16, 256, 0, stream>>>(xs1b, als1, ald1, edgedat, indptr, consts,
                                            b1, g1, be1, W2hi, W2lo, as2, ad2,
                                            xs2b, als2, ald2);
    gat2_agg<<<NN / 4, 256, 0, stream>>>(xs2b, als2, ald2, edgedat, indptr, consts,
                                         b2, g2, be2, Wc1, bc1, Wc2, bc2,
                                         Wr1, br1, Wr2, br2, out_h, out_cls, out_reg);
}

// Round 12
// 353.714 us; speedup vs baseline: 1.0424x; 1.0424x over previous
//
#include <hip/hip_runtime.h>
#include <cstdint>
#include <cstddef>

// ---------------- problem constants ----------------
#define NN 50000
#define EE 1600000
#define IN_DIM 256
#define HC 128      // HEADS*C
#define CD 32       // C
#define BN_RS 0.9999950000374997f  // 1/sqrt(1+1e-5)

#define CAP1 128
#define CAP2 128
#define NBKT 196        // ceil(NN/256) buckets of 256 dst nodes
#define S1_B 782        // (EE+2047)/2048
#define HIST_B 320
#define G1_B 782        // gemm1 blocks (4 waves x 16 rows)

typedef __attribute__((ext_vector_type(8))) short short8;   // 8 bf16 (bit pattern)
typedef __attribute__((ext_vector_type(4))) float f32x4;

// ---------------- small helpers ----------------
__device__ __forceinline__ float lrelu(float a) { return a > 0.f ? a : 0.2f * a; }
__device__ __forceinline__ float elu(float a) { return a > 0.f ? a : (__expf(a) - 1.f); }

__device__ __forceinline__ unsigned short f2bf(float f) {
    unsigned int u = __float_as_uint(f);
    unsigned int r = (u + 0x7FFFu + ((u >> 16) & 1u)) >> 16;
    return (unsigned short)r;
}
__device__ __forceinline__ float bf2f(unsigned short b) {
    return __uint_as_float(((unsigned int)b) << 16);
}
__device__ __forceinline__ float2 bf2f2(unsigned int p) {
    float2 r;
    r.x = __uint_as_float(p << 16);
    r.y = __uint_as_float(p & 0xFFFF0000u);
    return r;
}
__device__ __forceinline__ void unpack_edge(unsigned long long p, int& s, float& eav) {
    s = (int)(unsigned int)(p & 0xFFFFFFFFull);
    eav = __uint_as_float((unsigned int)(p >> 32));
}

// 256-thread exclusive scan (ONE internal barrier; all 256 must call)
__device__ __forceinline__ int block_excl_scan_256(int v, int tid, int* wsum) {
    int lane = tid & 63, wv = tid >> 6;
    int x = v;
    #pragma unroll
    for (int off = 1; off < 64; off <<= 1) {
        int y = __shfl_up(x, off);
        if (lane >= off) x += y;
    }
    if (lane == 63) wsum[wv] = x;
    __syncthreads();
    int wpre = 0;
    #pragma unroll
    for (int w = 0; w < 4; w++)
        if (w < wv) wpre += wsum[w];
    return wpre + x - v;
}

// ---------------- K0: W1/W2 frag prepack + attn consts + zero-init ----------------
__global__ __launch_bounds__(256) void k0_prep(const float* __restrict__ W1,
                                               const float* __restrict__ W2,
                                               const float* __restrict__ We1,
                                               const float* __restrict__ ae1,
                                               const float* __restrict__ We2,
                                               const float* __restrict__ ae2,
                                               unsigned short* __restrict__ W1hi,
                                               unsigned short* __restrict__ W1lo,
                                               unsigned short* __restrict__ W2hi,
                                               unsigned short* __restrict__ W2lo,
                                               float* __restrict__ consts,
                                               int* __restrict__ bucketHist) {
    int blk = blockIdx.x;
    int tid = threadIdx.x;
    if (blk < 16) {
        // W1 [256,128] -> frag order ((nt*8+kt)*64+lane)*8+j, split hi/lo
        int t = blk * 256 + tid;
        int lane = t & 63;
        int kt = (t >> 6) & 7;
        int nt = t >> 9;
        int kbase = kt * 32 + (lane >> 4) * 8;
        int col = nt * 16 + (lane & 15);
        size_t obase = (size_t)t * 8;
        #pragma unroll
        for (int j = 0; j < 8; j++) {
            float w = W1[(size_t)(kbase + j) * HC + col];
            unsigned short h = f2bf(w);
            W1hi[obase + j] = h;
            W1lo[obase + j] = f2bf(w - bf2f(h));
        }
    } else if (blk < 18) {
        // W2 [128,32] -> frag order ((nt*4+kt)*64+lane)*8+j, split hi/lo
        int t = (blk - 16) * 256 + tid;  // 0..511
        int lane = t & 63;
        int kt = (t >> 6) & 3;
        int nt = t >> 8;
        int kbase = kt * 32 + (lane >> 4) * 8;
        int col = nt * 16 + (lane & 15);
        size_t obase = (size_t)t * 8;
        #pragma unroll
        for (int j = 0; j < 8; j++) {
            float w = W2[(size_t)(kbase + j) * CD + col];
            unsigned short h = f2bf(w);
            W2hi[obase + j] = h;
            W2lo[obase + j] = f2bf(w - bf2f(h));
        }
    } else {
        if (tid < NBKT) bucketHist[tid] = 0;
        if (tid == 200) consts[0] = 0.f;     // easum accumulator
        if (tid < 4) {
            float s = 0.f;
            for (int c = 0; c < 32; c++) s += We1[tid * 32 + c] * ae1[tid * 32 + c];
            consts[2 + tid] = s;
        } else if (tid == 4) {
            float s = 0.f;
            for (int c = 0; c < 32; c++) s += We2[c] * ae2[c];
            consts[6] = s;
        }
    }
}

// ---------------- K_A: hist (LDS) + gemm1 (MFMA split-bf16), fused ----------------
__global__ __launch_bounds__(256) void kA_hist_gemm1(const int* __restrict__ ei,
                                                     const float* __restrict__ ea,
                                                     const float* __restrict__ x,
                                                     const unsigned short* __restrict__ Whi,
                                                     const unsigned short* __restrict__ Wlo,
                                                     int* __restrict__ bucketHist,
                                                     float* __restrict__ easum,
                                                     unsigned short* __restrict__ xs1b) {
    __shared__ int h[256];
    int tid = threadIdx.x;
    if (blockIdx.x < HIST_B) {
        h[tid] = 0;
        __syncthreads();
        float s = 0.f;
        for (int i = blockIdx.x * 256 + tid; i < EE; i += HIST_B * 256) {
            atomicAdd(&h[ei[EE + i] >> 8], 1);
            s += ea[i];
        }
        __syncthreads();
        if (tid < NBKT && h[tid] > 0) atomicAdd(&bucketHist[tid], h[tid]);
        #pragma unroll
        for (int off = 32; off > 0; off >>= 1) s += __shfl_xor(s, off);
        if ((tid & 63) == 0) atomicAdd(easum, s);
    } else {
        int lane = tid & 63, wv = tid >> 6;
        int row0 = (blockIdx.x - HIST_B) * 64 + wv * 16;
        if (row0 >= NN) return;
        int m = lane & 15;
        int q = lane >> 4;
        f32x4 acc[8];
        #pragma unroll
        for (int nt = 0; nt < 8; nt++) acc[nt] = {0.f, 0.f, 0.f, 0.f};
        const float* xrow = x + (size_t)(row0 + m) * IN_DIM + q * 8;
        #pragma unroll
        for (int kt = 0; kt < 8; kt++) {
            float4 v0 = *(const float4*)(xrow + kt * 32);
            float4 v1 = *(const float4*)(xrow + kt * 32 + 4);
            float vv[8] = {v0.x, v0.y, v0.z, v0.w, v1.x, v1.y, v1.z, v1.w};
            short8 ahi, alo;
            #pragma unroll
            for (int j = 0; j < 8; j++) {
                unsigned short hh = f2bf(vv[j]);
                ahi[j] = (short)hh;
                alo[j] = (short)f2bf(vv[j] - bf2f(hh));
            }
            #pragma unroll
            for (int nt = 0; nt < 8; nt++) {
                size_t fb = ((size_t)(nt * 8 + kt) * 64 + lane) * 8;
                short8 bhi = *(const short8*)(Whi + fb);
                short8 blo = *(const short8*)(Wlo + fb);
                acc[nt] = __builtin_amdgcn_mfma_f32_16x16x32_bf16(ahi, bhi, acc[nt], 0, 0, 0);
                acc[nt] = __builtin_amdgcn_mfma_f32_16x16x32_bf16(ahi, blo, acc[nt], 0, 0, 0);
                acc[nt] = __builtin_amdgcn_mfma_f32_16x16x32_bf16(alo, bhi, acc[nt], 0, 0, 0);
            }
        }
        #pragma unroll
        for (int nt = 0; nt < 8; nt++) {
            #pragma unroll
            for (int reg = 0; reg < 4; reg++) {
                int row = row0 + q * 4 + reg;
                xs1b[(size_t)row * HC + nt * 16 + m] = f2bf(acc[nt][reg]);
            }
        }
    }
}

// ---------------- bucket scan: bases + cursors + sentinels + ea_mean ----------------
__global__ void bucket_scan(const int* __restrict__ bucketHist,
                            int* __restrict__ bucketBase,
                            int* __restrict__ bucketCursor,
                            int* __restrict__ indptr,
                            float* __restrict__ consts) {
    __shared__ int wsum[4];
    int tid = threadIdx.x;  // 256
    int v = (tid < NBKT) ? bucketHist[tid] : 0;
    int excl = block_excl_scan_256(v, tid, wsum);
    if (tid <= NBKT) bucketBase[tid] = (tid == NBKT) ? EE : excl;
    if (tid < NBKT) bucketCursor[tid] = excl;
    if (tid == 0) { indptr[NN] = EE; consts[1] = consts[0] / (float)EE; }
}

// ---------------- K_B: stage1 (bucket bin) + al1, fused ----------------
__global__ __launch_bounds__(256) void kB_stage1_al1(const int* __restrict__ ei,
                                                     const float* __restrict__ ea,
                                                     int* __restrict__ bucketCursor,
                                                     int* __restrict__ Adst,
                                                     int* __restrict__ Asrc,
                                                     float* __restrict__ Aea,
                                                     const unsigned short* __restrict__ xs1b,
                                                     const float* __restrict__ as1,
                                                     const float* __restrict__ ad1,
                                                     float* __restrict__ als,
                                                     float* __restrict__ ald) {
    __shared__ int cnt[256];
    __shared__ int basel[256];
    __shared__ int gbase[256];
    __shared__ int wsum[4];
    __shared__ int sdst[2048];
    __shared__ int ssrc[2048];
    __shared__ float sea[2048];
    int tid = threadIdx.x;
    if (blockIdx.x < S1_B) {
        int base = blockIdx.x * 2048;
        cnt[tid] = 0;
        __syncthreads();
        int d[8], s[8], r[8], bk[8];
        float e[8];
        #pragma unroll
        for (int k = 0; k < 8; k++) {
            int i = base + k * 256 + tid;
            if (i < EE) {
                d[k] = ei[EE + i];
                s[k] = ei[i];
                e[k] = ea[i];
                bk[k] = d[k] >> 8;
                r[k] = atomicAdd(&cnt[bk[k]], 1);   // LDS returning atomic: cheap
            } else d[k] = -1;
        }
        __syncthreads();
        int v = cnt[tid];
        int excl = block_excl_scan_256(v, tid, wsum);
        basel[tid] = excl;
        if (tid < NBKT) gbase[tid] = atomicAdd(&bucketCursor[tid], v);
        __syncthreads();
        #pragma unroll
        for (int k = 0; k < 8; k++) {
            if (d[k] >= 0) {
                int slot = basel[bk[k]] + r[k];
                sdst[slot] = d[k];
                ssrc[slot] = s[k];
                sea[slot] = e[k];
            }
        }
        __syncthreads();
        int total = basel[255] + cnt[255];
        for (int slot = tid; slot < total; slot += 256) {
            int dd = sdst[slot];
            int b = dd >> 8;
            int pos = gbase[b] + (slot - basel[b]);
            Adst[pos] = dd;
            Asrc[pos] = ssrc[slot];
            Aea[pos] = sea[slot];
        }
    } else {
        // ---- al1 path: one thread per (node,head) ----
        int t = (blockIdx.x - S1_B) * 256 + tid;
        if (t < NN * 4) {
            int hh = t & 3;
            const unsigned int* xp = (const unsigned int*)(xs1b + (size_t)t * 32);
            const float* ap = as1 + hh * 32;
            const float* dp = ad1 + hh * 32;
            float s = 0.f, d = 0.f;
            #pragma unroll
            for (int q = 0; q < 16; q++) {
                float2 v = bf2f2(xp[q]);
                s += v.x * ap[q * 2] + v.y * ap[q * 2 + 1];
                d += v.x * dp[q * 2] + v.y * dp[q * 2 + 1];
            }
            als[t] = s;
            ald[t] = d;
        }
    }
}

// ---------------- stage2 (1024 threads): per-bucket counting sort -> indptr + edgedat ----
__global__ __launch_bounds__(1024) void stage2_kernel(const int* __restrict__ bucketBase,
                                                      const int* __restrict__ Adst,
                                                      const int* __restrict__ Asrc,
                                                      const float* __restrict__ Aea,
                                                      int* __restrict__ indptr,
                                                      unsigned long long* __restrict__ edgedat) {
    __shared__ int cnt[256];
    __shared__ int dbase[256];
    int tid = threadIdx.x;
    int b = blockIdx.x;
    int start = bucketBase[b], end = bucketBase[b + 1];
    if (tid < 256) cnt[tid] = 0;
    __syncthreads();
    for (int i = start + tid; i < end; i += 1024) atomicAdd(&cnt[Adst[i] & 255], 1);
    __syncthreads();
    // exclusive scan of 256 bins by wave 0 (4 bins/lane)
    if (tid < 64) {
        int b4 = tid * 4;
        int c0 = cnt[b4], c1 = cnt[b4 + 1], c2 = cnt[b4 + 2], c3 = cnt[b4 + 3];
        int t = c0 + c1 + c2 + c3;
        int x = t;
        #pragma unroll
        for (int off = 1; off < 64; off <<= 1) {
            int y = __shfl_up(x, off);
            if (tid >= off) x += y;
        }
        int e0 = x - t;
        dbase[b4] = e0;
        dbase[b4 + 1] = e0 + c0;
        dbase[b4 + 2] = e0 + c0 + c1;
        dbase[b4 + 3] = e0 + c0 + c1 + c2;
    }
    __syncthreads();
    if (tid < 256) {
        int n = b * 256 + tid;
        if (n < NN) indptr[n] = start + dbase[tid];
        cnt[tid] = 0;          // reuse as per-dst cursor
    }
    __syncthreads();
    for (int i = start + tid; i < end; i += 1024) {
        int dl = Adst[i] & 255;
        int r = atomicAdd(&cnt[dl], 1);
        int pos = start + dbase[dl] + r;
        edgedat[pos] = (unsigned long long)(unsigned int)Asrc[i] |
                       ((unsigned long long)__float_as_uint(Aea[i]) << 32);
    }
}

// ---------------- conv1 aggregation (no-max softmax) -> h1 as hi/lo bf16 ----------------
__global__ __launch_bounds__(256) void gat1_agg(
    const unsigned short* __restrict__ xs1b, const float* __restrict__ als,
    const float* __restrict__ ald, const unsigned long long* __restrict__ edgedat,
    const int* __restrict__ indptr, const float* __restrict__ consts,
    const float* __restrict__ b1, const float* __restrict__ g1,
    const float* __restrict__ be1,
    unsigned short* __restrict__ h1hi, unsigned short* __restrict__ h1lo) {
    __shared__ float exbuf[4][CAP1 * 4];
    __shared__ int srcbuf[4][CAP1];
    int wv = threadIdx.x >> 6;
    int lane = threadIdx.x & 63;
    int n = blockIdx.x * 4 + wv;
    int start = indptr[n];
    int deg = indptr[n + 1] - start;
    float ea_mean = consts[1];
    float ce[4] = {consts[2], consts[3], consts[4], consts[5]};
    float4 a4d = *(const float4*)(ald + (size_t)n * 4);
    float aldh[4] = {a4d.x, a4d.y, a4d.z, a4d.w};
    float4 a4s = *(const float4*)(als + (size_t)n * 4);
    float alsn[4] = {a4s.x, a4s.y, a4s.z, a4s.w};
    float ex0[4], sm[4];
    #pragma unroll
    for (int h = 0; h < 4; h++) {
        ex0[h] = __expf(lrelu(alsn[h] + aldh[h] + ea_mean * ce[h]));
        sm[h] = 0.f;
    }
    const unsigned long long* edp = edgedat + start;
    for (int i = lane; i < deg; i += 64) {
        int s; float eav;
        unpack_edge(edp[i], s, eav);
        float4 v4 = *(const float4*)(als + (size_t)s * 4);
        float alv[4] = {v4.x, v4.y, v4.z, v4.w};
        bool st = (i < CAP1);
        if (st) srcbuf[wv][i] = s * HC;
        #pragma unroll
        for (int h = 0; h < 4; h++) {
            float exv = __expf(lrelu(alv[h] + aldh[h] + eav * ce[h]));
            if (st) exbuf[wv][i * 4 + h] = exv;
            sm[h] += exv;
        }
    }
    #pragma unroll
    for (int h = 0; h < 4; h++)
        for (int off = 32; off > 0; off >>= 1) sm[h] += __shfl_xor(sm[h], off);
    float inv[4];
    #pragma unroll
    for (int h = 0; h < 4; h++) inv[h] = 1.0f / (sm[h] + ex0[h] + 1e-16f);
    int mcap = deg < CAP1 ? deg : CAP1;
    for (int i = lane; i < mcap; i += 64) {
        #pragma unroll
        for (int h = 0; h < 4; h++) exbuf[wv][i * 4 + h] *= inv[h];
    }
    int c = lane * 2;
    int h = lane >> 4;
    float wsl = ex0[h] * inv[h];
    float2 vself = bf2f2(*(const unsigned int*)(xs1b + (size_t)n * HC + c));
    float accx = vself.x * wsl, accy = vself.y * wsl;
    int i = 0;
    for (; i + 4 <= mcap; i += 4) {
        float w0 = exbuf[wv][(i + 0) * 4 + h];
        float w1 = exbuf[wv][(i + 1) * 4 + h];
        float w2 = exbuf[wv][(i + 2) * 4 + h];
        float w3 = exbuf[wv][(i + 3) * 4 + h];
        int o0 = srcbuf[wv][i + 0], o1 = srcbuf[wv][i + 1];
        int o2 = srcbuf[wv][i + 2], o3 = srcbuf[wv][i + 3];
        float2 v0 = bf2f2(*(const unsigned int*)(xs1b + o0 + c));
        float2 v1 = bf2f2(*(const unsigned int*)(xs1b + o1 + c));
        float2 v2 = bf2f2(*(const unsigned int*)(xs1b + o2 + c));
        float2 v3 = bf2f2(*(const unsigned int*)(xs1b + o3 + c));
        accx += v0.x * w0; accy += v0.y * w0;
        accx += v1.x * w1; accy += v1.y * w1;
        accx += v2.x * w2; accy += v2.y * w2;
        accx += v3.x * w3; accy += v3.y * w3;
    }
    for (; i < mcap; i++) {
        float w0 = exbuf[wv][i * 4 + h];
        int o0 = srcbuf[wv][i];
        float2 v0 = bf2f2(*(const unsigned int*)(xs1b + o0 + c));
        accx += v0.x * w0; accy += v0.y * w0;
    }
    for (; i < deg; i++) {  // spill fallback (deg > CAP1): recompute
        int s; float eav;
        unpack_edge(edp[i], s, eav);
        float a = lrelu(als[(size_t)s * 4 + h] + aldh[h] + eav * ce[h]);
        float w0 = __expf(a) * inv[h];
        float2 v0 = bf2f2(*(const unsigned int*)(xs1b + (size_t)s * HC + c));
        accx += v0.x * w0; accy += v0.y * w0;
    }
    float o0 = accx + b1[c];
    float o1 = accy + b1[c + 1];
    o0 = o0 * (g1[c] * BN_RS) + be1[c];
    o1 = o1 * (g1[c + 1] * BN_RS) + be1[c + 1];
    o0 = elu(o0);
    o1 = elu(o1);
    // split hi/lo bf16 for the MFMA gemm2
    unsigned short h0 = f2bf(o0), h1v = f2bf(o1);
    unsigned short l0 = f2bf(o0 - bf2f(h0)), l1 = f2bf(o1 - bf2f(h1v));
    *(unsigned int*)(h1hi + (size_t)n * HC + c) = (unsigned int)h0 | ((unsigned int)h1v << 16);
    *(unsigned int*)(h1lo + (size_t)n * HC + c) = (unsigned int)l0 | ((unsigned int)l1 << 16);
}

// ---------------- gemm2 via MFMA split-bf16 + fused al2 ----------------
__global__ __launch_bounds__(256) void gemm2_mfma(const unsigned short* __restrict__ h1hi,
                                                  const unsigned short* __restrict__ h1lo,
                                                  const unsigned short* __restrict__ W2hi,
                                                  const unsigned short* __restrict__ W2lo,
                                                  const float* __restrict__ as2,
                                                  const float* __restrict__ ad2,
                                                  unsigned short* __restrict__ xs2b,
                                                  float* __restrict__ als2,
                                                  float* __restrict__ ald2) {
    int tid = threadIdx.x;
    int lane = tid & 63, wv = tid >> 6;
    int row0 = blockIdx.x * 64 + wv * 16;
    if (row0 >= NN) return;
    int m = lane & 15, q = lane >> 4;
    f32x4 acc[2];
    acc[0] = {0.f, 0.f, 0.f, 0.f};
    acc[1] = {0.f, 0.f, 0.f, 0.f};
    const unsigned short* rhi = h1hi + (size_t)(row0 + m) * HC + q * 8;
    const unsigned short* rlo = h1lo + (size_t)(row0 + m) * HC + q * 8;
    #pragma unroll
    for (int kt = 0; kt < 4; kt++) {
        short8 ahi = *(const short8*)(rhi + kt * 32);
        short8 alo = *(const short8*)(rlo + kt * 32);
        #pragma unroll
        for (int nt = 0; nt < 2; nt++) {
            size_t fb = ((size_t)(nt * 4 + kt) * 64 + lane) * 8;
            short8 bhi = *(const short8*)(W2hi + fb);
            short8 blo = *(const short8*)(W2lo + fb);
            acc[nt] = __builtin_amdgcn_mfma_f32_16x16x32_bf16(ahi, bhi, acc[nt], 0, 0, 0);
            acc[nt] = __builtin_amdgcn_mfma_f32_16x16x32_bf16(ahi, blo, acc[nt], 0, 0, 0);
            acc[nt] = __builtin_amdgcn_mfma_f32_16x16x32_bf16(alo, bhi, acc[nt], 0, 0, 0);
        }
    }
    float a0 = as2[m], a1 = as2[m + 16];
    float d0 = ad2[m], d1 = ad2[m + 16];
    #pragma unroll
    for (int reg = 0; reg < 4; reg++) {
        int row = row0 + q * 4 + reg;
        xs2b[(size_t)row * CD + m]      = f2bf(acc[0][reg]);
        xs2b[(size_t)row * CD + 16 + m] = f2bf(acc[1][reg]);
        float s = acc[0][reg] * a0 + acc[1][reg] * a1;
        float d = acc[0][reg] * d0 + acc[1][reg] * d1;
        #pragma unroll
        for (int off = 1; off < 16; off <<= 1) {
            s += __shfl_xor(s, off);
            d += __shfl_xor(d, off);
        }
        if (m == 0) { als2[row] = s; ald2[row] = d; }
    }
}

// ---------------- conv2 aggregation + fused MLP heads (no-max softmax) ----------------
__global__ __launch_bounds__(256) void gat2_agg(
    const unsigned short* __restrict__ xs2b, const float* __restrict__ als,
    const float* __restrict__ ald, const unsigned long long* __restrict__ edgedat,
    const int* __restrict__ indptr, const float* __restrict__ consts,
    const float* __restrict__ b2, const float* __restrict__ g2, const float* __restrict__ be2,
    const float* __restrict__ Wc1, const float* __restrict__ bc1,
    const float* __restrict__ Wc2, const float* __restrict__ bc2,
    const float* __restrict__ Wr1, const float* __restrict__ br1,
    const float* __restrict__ Wr2, const float* __restrict__ br2,
    float* __restrict__ hout, float* __restrict__ cls, float* __restrict__ reg) {
    __shared__ float exbuf[4][CAP2];
    __shared__ int srcbuf[4][CAP2];
    __shared__ float hbuf[4][32];
    int wv = threadIdx.x >> 6;
    int lane = threadIdx.x & 63;
    int n = blockIdx.x * 4 + wv;
    int start = indptr[n];
    int deg = indptr[n + 1] - start;
    float ea_mean = consts[1];
    float ce = consts[6];
    float aldn = ald[n];
    float ex0 = __expf(lrelu(als[n] + aldn + ea_mean * ce));
    float sm = 0.f;
    const unsigned long long* edp = edgedat + start;
    for (int i = lane; i < deg; i += 64) {
        int s; float eav;
        unpack_edge(edp[i], s, eav);
        float exv = __expf(lrelu(als[s] + aldn + eav * ce));
        if (i < CAP2) { srcbuf[wv][i] = s * CD; exbuf[wv][i] = exv; }
        sm += exv;
    }
    for (int off = 32; off > 0; off >>= 1) sm += __shfl_xor(sm, off);
    float invd = 1.0f / (sm + ex0 + 1e-16f);
    int mcap = deg < CAP2 ? deg : CAP2;
    for (int i = lane; i < mcap; i += 64) exbuf[wv][i] *= invd;
    int quarter = lane >> 4;
    int cl = lane & 15;
    int c = cl * 2;
    float accx = 0.f, accy = 0.f;
    if (quarter == 0) {
        float2 vs = bf2f2(*(const unsigned int*)(xs2b + (size_t)n * CD + c));
        float wsl = ex0 * invd;
        accx = vs.x * wsl; accy = vs.y * wsl;
    }
    for (int i = quarter; i < mcap; i += 4) {
        float w0 = exbuf[wv][i];
        int o0 = srcbuf[wv][i];
        float2 v0 = bf2f2(*(const unsigned int*)(xs2b + o0 + c));
        accx += v0.x * w0; accy += v0.y * w0;
    }
    for (int i = CAP2 + quarter; i < deg; i += 4) {  // spill fallback
        int s; float eav;
        unpack_edge(edp[i], s, eav);
        float w0 = __expf(lrelu(als[s] + aldn + eav * ce)) * invd;
        float2 v0 = bf2f2(*(const unsigned int*)(xs2b + (size_t)s * CD + c));
        accx += v0.x * w0; accy += v0.y * w0;
    }
    accx += __shfl_xor(accx, 16); accy += __shfl_xor(accy, 16);
    accx += __shfl_xor(accx, 32); accy += __shfl_xor(accy, 32);
    if (lane < 16) {
        float o0 = accx + b2[c];
        float o1 = accy + b2[c + 1];
        o0 = o0 * (g2[c] * BN_RS) + be2[c];
        o1 = o1 * (g2[c + 1] * BN_RS) + be2[c + 1];
        o0 = elu(o0);
        o1 = elu(o1);
        hbuf[wv][c] = o0;
        hbuf[wv][c + 1] = o1;
        *(float2*)(hout + (size_t)n * CD + c) = make_float2(o0, o1);
    }
    __syncthreads();
    float r0 = 0.f, r1 = 0.f;
    if (lane < 32) {
        int j = lane & 15;
        bool iscls = lane < 16;
        float s = iscls ? bc1[j] : br1[j];
        #pragma unroll
        for (int cc = 0; cc < 32; cc++) {
            float w = iscls ? Wc1[cc * 16 + j] : Wr1[cc * 16 + j];
            s += hbuf[wv][cc] * w;
        }
        s = fmaxf(s, 0.f);
        if (iscls) { r0 = s * Wc2[j * 2]; r1 = s * Wc2[j * 2 + 1]; }
        else       { r0 = s * Wr2[j]; }
    }
    #pragma unroll
    for (int off = 1; off < 16; off <<= 1) {
        r0 += __shfl_xor(r0, off);
        r1 += __shfl_xor(r1, off);
    }
    if (lane == 0)  *(float2*)(cls + (size_t)n * 2) = make_float2(r0 + bc2[0], r1 + bc2[1]);
    if (lane == 16) reg[n] = r0 + br2[0];
}

// ---------------- launch ----------------
extern "C" void kernel_launch(void* const* d_in, const int* in_sizes, int n_in,
                              void* d_out, int out_size, void* d_ws, size_t ws_size,
                              hipStream_t stream) {
    const float* x   = (const float*)d_in[0];
    const int*   ei  = (const int*)d_in[1];
    const float* ea  = (const float*)d_in[2];
    const float* W1  = (const float*)d_in[3];
    const float* as1 = (const float*)d_in[4];
    const float* ad1 = (const float*)d_in[5];
    const float* We1 = (const float*)d_in[6];
    const float* ae1 = (const float*)d_in[7];
    const float* b1  = (const float*)d_in[8];
    const float* g1  = (const float*)d_in[9];
    const float* be1 = (const float*)d_in[10];
    const float* W2  = (const float*)d_in[11];
    const float* as2 = (const float*)d_in[12];
    const float* ad2 = (const float*)d_in[13];
    const float* We2 = (const float*)d_in[14];
    const float* ae2 = (const float*)d_in[15];
    const float* b2  = (const float*)d_in[16];
    const float* g2  = (const float*)d_in[17];
    const float* be2 = (const float*)d_in[18];
    const float* Wc1 = (const float*)d_in[19];
    const float* bc1 = (const float*)d_in[20];
    const float* Wc2 = (const float*)d_in[21];
    const float* bc2 = (const float*)d_in[22];
    const float* Wr1 = (const float*)d_in[23];
    const float* br1 = (const float*)d_in[24];
    const float* Wr2 = (const float*)d_in[25];
    const float* br2 = (const float*)d_in[26];

    char* ws = (char*)d_ws;
    unsigned short* xs1b = (unsigned short*)(ws + 0);          // N*128 bf16 = 12.8 MB
    unsigned short* h1hi = (unsigned short*)(ws + 12800000);   // N*128 bf16 = 12.8 MB
    unsigned short* h1lo = (unsigned short*)(ws + 25600000);   // N*128 bf16 = 12.8 MB
    // staging arrays alias h1hi/h1lo (consumed by stage2 before gat1 writes them)
    int*   Adst          = (int*)(ws + 12800000);              // E = 6.4 MB
    int*   Asrc          = (int*)(ws + 19200000);              // E = 6.4 MB
    float* Aea           = (float*)(ws + 25600000);            // E = 6.4 MB (ends 32.0 MB)
    unsigned short* xs2b = (unsigned short*)(ws + 38400000);   // N*32 bf16 = 3.2 MB
    float* als1          = (float*)(ws + 41600000);            // N*4
    float* ald1          = (float*)(ws + 42400000);            // N*4
    float* als2          = (float*)(ws + 43200000);            // N
    float* ald2          = (float*)(ws + 43400000);            // N
    float* consts        = (float*)(ws + 43600000);            // 8 floats
    int*   bucketHist    = (int*)(ws + 43600128);              // 196
    int*   bucketBase    = (int*)(ws + 43601024);              // 197
    int*   bucketCursor  = (int*)(ws + 43601920);              // 196
    int*   indptr        = (int*)(ws + 43602816);              // N+1
    unsigned long long* edgedat = (unsigned long long*)(ws + 43802824);  // E*8 -> ends 56602824
    unsigned short* W1hi = (unsigned short*)(ws + 56602832);   // 64 KB
    unsigned short* W1lo = (unsigned short*)(ws + 56668368);   // 64 KB
    unsigned short* W2hi = (unsigned short*)(ws + 56733904);   // 8 KB
    unsigned short* W2lo = (unsigned short*)(ws + 56742096);   // 8 KB (ends ~56.75 MB)

    float* out_cls = (float*)d_out;            // [N,2]
    float* out_reg = out_cls + 2 * NN;         // [N]
    float* out_h   = out_cls + 3 * NN;         // [N,32]

    // K0: weight prepacks + attn consts + zero-init (replaces memsets)
    k0_prep<<<19, 256, 0, stream>>>(W1, W2, We1, ae1, We2, ae2,
                                    W1hi, W1lo, W2hi, W2lo, consts, bucketHist);
    // K_A: hist + gemm1 fused
    kA_hist_gemm1<<<HIST_B + G1_B, 256, 0, stream>>>(ei, ea, x, W1hi, W1lo,
                                                     bucketHist, consts, xs1b);
    bucket_scan<<<1, 256, 0, stream>>>(bucketHist, bucketBase, bucketCursor, indptr, consts);
    // K_B: stage1 + al1 fused
    kB_stage1_al1<<<S1_B + 782, 256, 0, stream>>>(ei, ea, bucketCursor, Adst, Asrc, Aea,
                                                  xs1b, as1, ad1, als1, ald1);
    // stage2: 1024 threads/block for full-machine occupancy at 196 blocks
    stage2_kernel<<<NBKT, 1024, 0, stream>>>(bucketBase, Adst, Asrc, Aea, indptr, edgedat);

    // gat1 (writes h1 as hi/lo bf16)
    gat1_agg<<<NN / 4, 256, 0, stream>>>(xs1b, als1, ald1, edgedat, indptr, consts,
                                         b1, g1, be1, h1hi, h1lo);
    // conv2: MFMA gemm2 + fused al2
    gemm2_mfma<<<G1_B, 256, 0, stream>>>(h1hi, h1lo, W2hi, W2lo, as2, ad2,
                                         xs2b, als2, ald2);
    gat2_agg<<<NN / 4, 256, 0, stream>>>(xs2b, als2, ald2, edgedat, indptr, consts,
                                         b2, g2, be2, Wc1, bc1, Wc2, bc2,
                                         Wr1, br1, Wr2, br2, out_h, out_cls, out_reg);
}